// Round 7
// baseline (51.039 us; speedup 1.0000x reference)
//
#include <hip/hip_runtime.h>
#include <hip/hip_bf16.h>

// out[b,n] = sum_k x[b,k] * weight[indices[n],k]
// M=64, N=4403, K=4096, fp32 in/out.
// R7: R5/R6 invariance => GEMM pinned by gathered-weight L3 streaming, aux
// structure (cvt launch + 9.4MB partials + 10.5MB cross-XCD reduce + 3 launch
// gaps) costs the rest. New shape:
//   prep: one kernel, disjoint blocks zero d_out / convert x->bf16 (ws)
//   gemm: no LDS, no partials. wave = 16n x 64batch x 512k stripe; one weight
//         b-frag feeds 4 MFMAs (no cross-wave weight duplication); epilogue
//         accumulates straight into out via fp32 atomics.

#define HIDDEN 4096
#define KSPLIT 8
#define KCHUNK (HIDDEN / KSPLIT)   // 512
#define KSTEPS (KCHUNK / 32)       // 16
#define BATCH  64

using short8 = __attribute__((ext_vector_type(8))) short;
using f32x4  = __attribute__((ext_vector_type(4))) float;

__device__ __forceinline__ short f2bf(float f) {
    __bf16 h = (__bf16)f;                 // pairs into v_cvt_pk_bf16_f32
    return __builtin_bit_cast(short, h);
}

__device__ __forceinline__ short8 cvt8(const f32x4& lo, const f32x4& hi) {
    short8 r;
    r[0] = f2bf(lo[0]); r[1] = f2bf(lo[1]); r[2] = f2bf(lo[2]); r[3] = f2bf(lo[3]);
    r[4] = f2bf(hi[0]); r[5] = f2bf(hi[1]); r[6] = f2bf(hi[2]); r[7] = f2bf(hi[3]);
    return r;
}

// ---- prep: blocks [0,ZB) zero d_out; blocks [ZB,ZB+128) convert x to bf16 --
#define ZBLOCKS 276
__global__ __launch_bounds__(256) void prep(
    const float* __restrict__ x, unsigned short* __restrict__ xbf,
    float* __restrict__ out, int nout4)
{
    const int b = blockIdx.x;
    const int t = threadIdx.x;
    if (b < ZBLOCKS) {
        const int i = b * 256 + t;
        if (i < nout4) {
            f32x4 z = {0.f, 0.f, 0.f, 0.f};
            ((f32x4*)out)[i] = z;
        }
    } else {
        const int i = ((b - ZBLOCKS) * 256 + t) * 8;
        f32x4 a = *(const f32x4*)(x + i);
        f32x4 c = *(const f32x4*)(x + i + 4);
        *(short8*)(xbf + i) = cvt8(a, c);
    }
}

// ---- gemm: 4 independent waves per block (4 consecutive n-tiles) -----------
__global__ __launch_bounds__(256, 4) void gather_gemm(
    const float*          __restrict__ weight,   // [11008, 4096] f32
    const unsigned short* __restrict__ xbf,      // [64, 4096] bf16
    const int*            __restrict__ indices,  // [R]
    float*                __restrict__ out,      // [64, R], pre-zeroed
    int R)
{
    const int t    = threadIdx.x;
    const int lane = t & 63;
    const int wave = t >> 6;
    const int nl   = lane & 15;
    const int kg   = lane >> 4;
    const int nb   = blockIdx.x * 4 + wave;   // n-tile of 16
    const int kb   = blockIdx.y;              // K-chunk of 512

    const int n   = nb * 16 + nl;
    const int row = indices[n < R ? n : R - 1];

    const float* wp = weight + (size_t)row * HIDDEN + kb * KCHUNK + kg * 8;
    const unsigned short* xp = xbf + kb * KCHUNK + kg * 8;

    f32x4 acc0 = {0.f,0.f,0.f,0.f}, acc1 = {0.f,0.f,0.f,0.f};
    f32x4 acc2 = {0.f,0.f,0.f,0.f}, acc3 = {0.f,0.f,0.f,0.f};

#pragma unroll
    for (int ks = 0; ks < KSTEPS; ++ks) {
        f32x4 w0 = *(const f32x4*)(wp + ks * 32);
        f32x4 w1 = *(const f32x4*)(wp + ks * 32 + 4);
        short8 b = cvt8(w0, w1);

        short8 a0 = *(const short8*)(xp + (size_t)(0 * 16 + nl) * HIDDEN + ks * 32);
        short8 a1 = *(const short8*)(xp + (size_t)(1 * 16 + nl) * HIDDEN + ks * 32);
        short8 a2 = *(const short8*)(xp + (size_t)(2 * 16 + nl) * HIDDEN + ks * 32);
        short8 a3 = *(const short8*)(xp + (size_t)(3 * 16 + nl) * HIDDEN + ks * 32);

        acc0 = __builtin_amdgcn_mfma_f32_16x16x32_bf16(a0, b, acc0, 0, 0, 0);
        acc1 = __builtin_amdgcn_mfma_f32_16x16x32_bf16(a1, b, acc1, 0, 0, 0);
        acc2 = __builtin_amdgcn_mfma_f32_16x16x32_bf16(a2, b, acc2, 0, 0, 0);
        acc3 = __builtin_amdgcn_mfma_f32_16x16x32_bf16(a3, b, acc3, 0, 0, 0);
    }

    // C/D: col = nl (n), row = kg*4 + r within each 16-row m-tile
    if (n < R) {
        const f32x4 accs[4] = {acc0, acc1, acc2, acc3};
#pragma unroll
        for (int m = 0; m < 4; ++m) {
#pragma unroll
            for (int r = 0; r < 4; ++r) {
                const int brow = m * 16 + kg * 4 + r;
                unsafeAtomicAdd(&out[(size_t)brow * R + n], accs[m][r]);
            }
        }
    }
}

extern "C" void kernel_launch(void* const* d_in, const int* in_sizes, int n_in,
                              void* d_out, int out_size, void* d_ws, size_t ws_size,
                              hipStream_t stream) {
    const float* x       = (const float*)d_in[0];
    const float* weight  = (const float*)d_in[1];
    const int*   indices = (const int*)d_in[2];
    float*       out     = (float*)d_out;
    unsigned short* xbf  = (unsigned short*)d_ws;

    const int R = in_sizes[2];                 // 4403
    const int nout4 = out_size / 4;            // 70448
    const int cvt_blocks = (BATCH * HIDDEN) / (256 * 8);   // 128

    prep<<<dim3(ZBLOCKS + cvt_blocks), dim3(256), 0, stream>>>(x, xbf, out, nout4);

    const int nb4 = (R + 63) / 64;             // 69 blocks of 4 waves -> 276 n-tiles
    gather_gemm<<<dim3(nb4, KSPLIT), dim3(256), 0, stream>>>(weight, xbf, indices, out, R);
}

// Round 8
// 34.936 us; speedup vs baseline: 1.4609x; 1.4609x over previous
//
#include <hip/hip_runtime.h>
#include <hip/hip_bf16.h>

// out[b,n] = sum_k x[b,k] * weight[indices[n],k]
// M=64, N=4403, K=4096, fp32 in/out.
// R8: R7's direct atomics caused 8-way cross-XCD line bouncing (51us) ->
// back to partials+reduce. GEMM fixes vs R6:
//   - KSPLIT 8->4: KCHUNK=1024 as TWO staged 512-sub-chunks through one
//     32KB LDS buffer, same acc (halves partials: 9.4->4.7MB)
//   - T14 async-STAGE: sub1's 16 dwordx4 weight loads ISSUED before sub0's
//     compute, drained after the barrier -> stage latency hidden under MFMA
//   - acc only 8 VGPR (2 n-frags); ~160 VGPR total -> 3 blocks/CU

#define HIDDEN 4096
#define KSPLIT 4
#define KCHUNK (HIDDEN / KSPLIT)   // 1024
#define SUB    512                 // staged sub-chunk
#define SSTEPS (SUB / 32)          // 16 K-steps per sub-chunk
#define BATCH  64
#define NTILE  32
#define XBF_OFF (16u << 20)        // byte offset of x_bf16 inside ws

using short8 = __attribute__((ext_vector_type(8))) short;
using f32x4  = __attribute__((ext_vector_type(4))) float;

__device__ __forceinline__ short f2bf(float f) {
    __bf16 h = (__bf16)f;                 // pairs into v_cvt_pk_bf16_f32
    return __builtin_bit_cast(short, h);
}

__device__ __forceinline__ short8 cvt8(const f32x4& lo, const f32x4& hi) {
    short8 r;
    r[0] = f2bf(lo[0]); r[1] = f2bf(lo[1]); r[2] = f2bf(lo[2]); r[3] = f2bf(lo[3]);
    r[4] = f2bf(hi[0]); r[5] = f2bf(hi[1]); r[6] = f2bf(hi[2]); r[7] = f2bf(hi[3]);
    return r;
}

// ---- k0: convert x to bf16 -------------------------------------------------
__global__ __launch_bounds__(256) void cvt_x(
    const float* __restrict__ x, unsigned short* __restrict__ xbf)
{
    const int i = (blockIdx.x * 256 + threadIdx.x) * 8;
    f32x4 a = *(const f32x4*)(x + i);
    f32x4 b = *(const f32x4*)(x + i + 4);
    *(short8*)(xbf + i) = cvt8(a, b);
}

// ---- k1: gathered GEMM, two async-staged sub-chunks ------------------------
__global__ __launch_bounds__(256, 2) void gather_gemm(
    const float*          __restrict__ weight,   // [11008, 4096] f32
    const unsigned short* __restrict__ xbf,      // [64, 4096] bf16
    const int*            __restrict__ indices,  // [R]
    float*                __restrict__ ws,       // [KSPLIT, 64, R] partials
    int R)
{
    __shared__ unsigned short wlds[NTILE * SUB];   // 32 KB, XOR-swizzled

    const int t    = threadIdx.x;
    const int lane = t & 63;
    const int wave = t >> 6;
    const int nl   = lane & 15;
    const int kg   = lane >> 4;
    const int nb   = blockIdx.x;   // N-tile of 32
    const int kb   = blockIdx.y;   // K-chunk of 1024
    const int k0   = kb * KCHUNK;

    // staging mapping: 8 threads/row, thread covers cols (t&7)*8 + s*64
    const int sr = t >> 3;         // 0..31
    const int sc = t & 7;          // 0..7
    const int ns = nb * NTILE + sr;
    const int wrow = indices[ns < R ? ns : R - 1];
    const float* wsrc = weight + (size_t)wrow * HIDDEN + k0 + sc * 8;
    char* ldsrow = (char*)wlds + sr * (SUB * 2);
    const unsigned int swz = (unsigned int)((sr & 7) << 4);

    f32x4 sreg[16];

    // ---- stage sub0 ----
#pragma unroll
    for (int s = 0; s < 8; ++s) {
        sreg[2*s]   = *(const f32x4*)(wsrc + s * 64);
        sreg[2*s+1] = *(const f32x4*)(wsrc + s * 64 + 4);
    }
#pragma unroll
    for (int s = 0; s < 8; ++s) {
        short8 h = cvt8(sreg[2*s], sreg[2*s+1]);
        *(short8*)(ldsrow + ((unsigned int)(sc * 16 + s * 128) ^ swz)) = h;
    }

    // a-frags for sub0
    const unsigned short* xrow =
        xbf + (size_t)(wave * 16 + nl) * HIDDEN + k0 + kg * 8;
    short8 afr[SSTEPS];
#pragma unroll
    for (int ks = 0; ks < SSTEPS; ++ks)
        afr[ks] = *(const short8*)(xrow + ks * 32);

    __syncthreads();

    // ---- issue sub1 stage loads NOW (in flight across sub0 compute) ----
#pragma unroll
    for (int s = 0; s < 8; ++s) {
        sreg[2*s]   = *(const f32x4*)(wsrc + SUB + s * 64);
        sreg[2*s+1] = *(const f32x4*)(wsrc + SUB + s * 64 + 4);
    }

    f32x4 acc0 = {0.f,0.f,0.f,0.f}, acc1 = {0.f,0.f,0.f,0.f};

    // ---- compute sub0 ----
#pragma unroll
    for (int ks = 0; ks < SSTEPS; ++ks) {
#pragma unroll
        for (int nf = 0; nf < 2; ++nf) {
            const int rr = nf * 16 + nl;
            const unsigned int bc =
                (unsigned int)(ks * 64 + kg * 16) ^ (unsigned int)((rr & 7) << 4);
            short8 b = *(const short8*)((const char*)wlds + rr * (SUB * 2) + bc);
            f32x4& acc = nf == 0 ? acc0 : acc1;
            acc = __builtin_amdgcn_mfma_f32_16x16x32_bf16(afr[ks], b, acc, 0, 0, 0);
        }
    }

    __syncthreads();   // all waves done reading buf

    // ---- write sub1 (compiler drains vmcnt here), reload a-frags ----
#pragma unroll
    for (int s = 0; s < 8; ++s) {
        short8 h = cvt8(sreg[2*s], sreg[2*s+1]);
        *(short8*)(ldsrow + ((unsigned int)(sc * 16 + s * 128) ^ swz)) = h;
    }
#pragma unroll
    for (int ks = 0; ks < SSTEPS; ++ks)
        afr[ks] = *(const short8*)(xrow + SUB + ks * 32);

    __syncthreads();

    // ---- compute sub1 (accumulate into same acc) ----
#pragma unroll
    for (int ks = 0; ks < SSTEPS; ++ks) {
#pragma unroll
        for (int nf = 0; nf < 2; ++nf) {
            const int rr = nf * 16 + nl;
            const unsigned int bc =
                (unsigned int)(ks * 64 + kg * 16) ^ (unsigned int)((rr & 7) << 4);
            short8 b = *(const short8*)((const char*)wlds + rr * (SUB * 2) + bc);
            f32x4& acc = nf == 0 ? acc0 : acc1;
            acc = __builtin_amdgcn_mfma_f32_16x16x32_bf16(afr[ks], b, acc, 0, 0, 0);
        }
    }

    // ---- store partials: C/D col = nl (n), row = kg*4 + r ----
    float* part = ws + (size_t)kb * BATCH * R;
    f32x4 accs[2] = {acc0, acc1};
#pragma unroll
    for (int nf = 0; nf < 2; ++nf) {
        const int nn = nb * NTILE + nf * 16 + nl;
        if (nn < R) {
#pragma unroll
            for (int r = 0; r < 4; ++r) {
                const int brow = wave * 16 + kg * 4 + r;
                part[(size_t)brow * R + nn] = accs[nf][r];
            }
        }
    }
}

// ---- k2: sum KSPLIT partials ----------------------------------------------
__global__ __launch_bounds__(256) void reduce_partials(
    const float* __restrict__ ws, float* __restrict__ out, int n4, int stride4)
{
    const int i = blockIdx.x * blockDim.x + threadIdx.x;
    if (i >= n4) return;
    const f32x4* w = (const f32x4*)ws;
    f32x4 s = w[i];
#pragma unroll
    for (int kb = 1; kb < KSPLIT; ++kb) {
        f32x4 v = w[(size_t)kb * stride4 + i];
        s[0] += v[0]; s[1] += v[1]; s[2] += v[2]; s[3] += v[3];
    }
    ((f32x4*)out)[i] = s;
}

extern "C" void kernel_launch(void* const* d_in, const int* in_sizes, int n_in,
                              void* d_out, int out_size, void* d_ws, size_t ws_size,
                              hipStream_t stream) {
    const float* x       = (const float*)d_in[0];
    const float* weight  = (const float*)d_in[1];
    const int*   indices = (const int*)d_in[2];
    float*       out     = (float*)d_out;
    float*       ws      = (float*)d_ws;
    unsigned short* xbf  = (unsigned short*)((char*)d_ws + XBF_OFF);

    const int R  = in_sizes[2];                   // 4403
    const int nb = (R + NTILE - 1) / NTILE;       // 138

    cvt_x<<<dim3((BATCH * HIDDEN) / (256 * 8)), dim3(256), 0, stream>>>(x, xbf);
    gather_gemm<<<dim3(nb, KSPLIT), dim3(256), 0, stream>>>(weight, xbf, indices, ws, R);

    const int n4 = (BATCH * R) / 4;
    reduce_partials<<<dim3((n4 + 255) / 256), dim3(256), 0, stream>>>(ws, out, n4, n4);
}

// Round 9
// 34.593 us; speedup vs baseline: 1.4754x; 1.0099x over previous
//
#include <hip/hip_runtime.h>
#include <hip/hip_bf16.h>

// out[b,n] = sum_k x[b,k] * weight[indices[n],k]
// M=64, N=4403, K=4096, fp32 in/out.
// R9: R5/R6/R8 all realize ~5.5 TB/s VMEM (reg-staged load->cvt->ds_write).
// m102/m151 show global_load_lds staging reaches ~13 TB/s on this chip.
// Swap staging to global_load_lds dwordx4 with PRE-SWIZZLED per-lane global
// source (LDS dest must be linear); weight staged as f32, cvt to bf16 in the
// inner loop. cvt_x + partials(KSPLIT=8) + nt-load reduce unchanged.

#define HIDDEN 4096
#define KSPLIT 8
#define KCHUNK (HIDDEN / KSPLIT)   // 512
#define KSTEPS (KCHUNK / 32)       // 16
#define BATCH  64
#define NTILE  32
#define XBF_OFF (16u << 20)        // byte offset of x_bf16 inside ws

using short8 = __attribute__((ext_vector_type(8))) short;
using f32x4  = __attribute__((ext_vector_type(4))) float;

typedef const void __attribute__((address_space(1))) gvoid;
typedef void __attribute__((address_space(3))) svoid;

__device__ __forceinline__ short f2bf(float f) {
    __bf16 h = (__bf16)f;                 // pairs into v_cvt_pk_bf16_f32
    return __builtin_bit_cast(short, h);
}

__device__ __forceinline__ short8 cvt8(const f32x4& lo, const f32x4& hi) {
    short8 r;
    r[0] = f2bf(lo[0]); r[1] = f2bf(lo[1]); r[2] = f2bf(lo[2]); r[3] = f2bf(lo[3]);
    r[4] = f2bf(hi[0]); r[5] = f2bf(hi[1]); r[6] = f2bf(hi[2]); r[7] = f2bf(hi[3]);
    return r;
}

// ---- k0: convert x to bf16 -------------------------------------------------
__global__ __launch_bounds__(256) void cvt_x(
    const float* __restrict__ x, unsigned short* __restrict__ xbf)
{
    const int i = (blockIdx.x * 256 + threadIdx.x) * 8;
    f32x4 a = *(const f32x4*)(x + i);
    f32x4 b = *(const f32x4*)(x + i + 4);
    *(short8*)(xbf + i) = cvt8(a, b);
}

// ---- k1: gathered GEMM, global_load_lds staging (f32 in LDS) ---------------
__global__ __launch_bounds__(256, 2) void gather_gemm(
    const float*          __restrict__ weight,   // [11008, 4096] f32
    const unsigned short* __restrict__ xbf,      // [64, 4096] bf16
    const int*            __restrict__ indices,  // [R]
    float*                __restrict__ ws,       // [KSPLIT, 64, R] partials
    int R)
{
    __shared__ float wlds[NTILE * KCHUNK];   // 64 KB f32; LDS[L] = glb[L^swz]

    const int t    = threadIdx.x;
    const int lane = t & 63;
    const int wave = t >> 6;
    const int nl   = lane & 15;
    const int kg   = lane >> 4;
    const int nb   = blockIdx.x;   // N-tile of 32
    const int kb   = blockIdx.y;   // K-chunk of 512
    const int k0   = kb * KCHUNK;

    // ---- stage: wave stages rows wave*8..+7; 2 x global_load_lds(16B)/row --
    // LDS dest linear (wave-uniform base + lane*16); global src pre-swizzled:
    // src col-byte = (h*1024 + lane*16) ^ ((r&7)<<4)   (involution)
    {
        const int r0 = wave * 8;
#pragma unroll
        for (int j = 0; j < 8; ++j) {
            const int r = r0 + j;
            const int n = nb * NTILE + r;
            const int wrow = indices[n < R ? n : R - 1];
            const char* rowp = (const char*)(weight + (size_t)wrow * HIDDEN + k0);
            const unsigned int swz = (unsigned int)((r & 7) << 4);
#pragma unroll
            for (int h = 0; h < 2; ++h) {
                const unsigned int srcoff =
                    ((unsigned int)(h * 1024 + lane * 16)) ^ swz;
                __builtin_amdgcn_global_load_lds(
                    (gvoid*)(rowp + srcoff),
                    (svoid*)((char*)wlds + r * 2048 + h * 1024),
                    16, 0, 0);
            }
        }
    }

    // ---- preload a-frags (x bf16) into registers ---------------------------
    const unsigned short* xrow =
        xbf + (size_t)(wave * 16 + nl) * HIDDEN + k0 + kg * 8;
    short8 afr[KSTEPS];
#pragma unroll
    for (int ks = 0; ks < KSTEPS; ++ks)
        afr[ks] = *(const short8*)(xrow + ks * 32);

    __syncthreads();   // compiler drains vmcnt(0) here

    // ---- K loop: {4 ds_read_b128 f32 + 8 cvt_pk + 2 MFMA} per step ---------
    f32x4 acc0 = {0.f,0.f,0.f,0.f}, acc1 = {0.f,0.f,0.f,0.f};

#pragma unroll
    for (int ks = 0; ks < KSTEPS; ++ks) {
#pragma unroll
        for (int nf = 0; nf < 2; ++nf) {
            const int rr = nf * 16 + nl;
            const unsigned int swz = (unsigned int)((rr & 7) << 4);
            const unsigned int g0 = (unsigned int)(ks * 128 + kg * 32);
            const char* rowbase = (const char*)wlds + rr * 2048;
            f32x4 w0 = *(const f32x4*)(rowbase + (g0 ^ swz));
            f32x4 w1 = *(const f32x4*)(rowbase + ((g0 + 16) ^ swz));
            short8 b = cvt8(w0, w1);
            f32x4& acc = nf == 0 ? acc0 : acc1;
            acc = __builtin_amdgcn_mfma_f32_16x16x32_bf16(afr[ks], b, acc, 0, 0, 0);
        }
    }

    // ---- store partials: C/D col = nl (n), row = kg*4 + r ------------------
    float* part = ws + (size_t)kb * BATCH * R;
    f32x4 accs[2] = {acc0, acc1};
#pragma unroll
    for (int nf = 0; nf < 2; ++nf) {
        const int nn = nb * NTILE + nf * 16 + nl;
        if (nn < R) {
#pragma unroll
            for (int r = 0; r < 4; ++r) {
                const int brow = wave * 16 + kg * 4 + r;
                part[(size_t)brow * R + nn] = accs[nf][r];
            }
        }
    }
}

// ---- k2: sum KSPLIT partials (nontemporal loads) ---------------------------
__global__ __launch_bounds__(256) void reduce_partials(
    const float* __restrict__ ws, float* __restrict__ out, int n4, int stride4)
{
    const int i = blockIdx.x * blockDim.x + threadIdx.x;
    if (i >= n4) return;
    const f32x4* w = (const f32x4*)ws;
    f32x4 s = __builtin_nontemporal_load(&w[i]);
#pragma unroll
    for (int kb = 1; kb < KSPLIT; ++kb) {
        f32x4 v = __builtin_nontemporal_load(&w[(size_t)kb * stride4 + i]);
        s[0] += v[0]; s[1] += v[1]; s[2] += v[2]; s[3] += v[3];
    }
    ((f32x4*)out)[i] = s;
}

extern "C" void kernel_launch(void* const* d_in, const int* in_sizes, int n_in,
                              void* d_out, int out_size, void* d_ws, size_t ws_size,
                              hipStream_t stream) {
    const float* x       = (const float*)d_in[0];
    const float* weight  = (const float*)d_in[1];
    const int*   indices = (const int*)d_in[2];
    float*       out     = (float*)d_out;
    float*       ws      = (float*)d_ws;
    unsigned short* xbf  = (unsigned short*)((char*)d_ws + XBF_OFF);

    const int R  = in_sizes[2];                   // 4403
    const int nb = (R + NTILE - 1) / NTILE;       // 138

    cvt_x<<<dim3((BATCH * HIDDEN) / (256 * 8)), dim3(256), 0, stream>>>(x, xbf);
    gather_gemm<<<dim3(nb, KSPLIT), dim3(256), 0, stream>>>(weight, xbf, indices, ws, R);

    const int n4 = (BATCH * R) / 4;
    reduce_partials<<<dim3((n4 + 255) / 256), dim3(256), 0, stream>>>(ws, out, n4, n4);
}